// Round 1
// baseline (4015.766 us; speedup 1.0000x reference)
//
#include <hip/hip_runtime.h>

// LightGCN conv: user_out = A @ item_emb ; item_out = A^T @ user_emb, A in COO.
// One wave per edge, one lane per dim (DIM==64 == wavefront size).
// All gathers and atomics are 256B coalesced segments.

constexpr int DIM = 64;

__global__ void lightgcn_scatter(const float* __restrict__ user_emb,
                                 const float* __restrict__ item_emb,
                                 const int* __restrict__ rows,
                                 const int* __restrict__ cols,
                                 const float* __restrict__ vals,
                                 float* __restrict__ user_out,
                                 float* __restrict__ item_out,
                                 int nnz) {
    const int lane   = threadIdx.x & 63;
    const int wave   = (blockIdx.x * blockDim.x + threadIdx.x) >> 6;
    const int nwaves = (gridDim.x * blockDim.x) >> 6;

    for (int e = wave; e < nnz; e += nwaves) {
        const int   r = rows[e];
        const int   c = cols[e];
        const float v = vals[e];

        const float it = item_emb[(size_t)c * DIM + lane];
        const float us = user_emb[(size_t)r * DIM + lane];

        atomicAdd(&user_out[(size_t)r * DIM + lane], v * it);
        atomicAdd(&item_out[(size_t)c * DIM + lane], v * us);
    }
}

extern "C" void kernel_launch(void* const* d_in, const int* in_sizes, int n_in,
                              void* d_out, int out_size, void* d_ws, size_t ws_size,
                              hipStream_t stream) {
    const float* user_emb = (const float*)d_in[0];
    const float* item_emb = (const float*)d_in[1];
    const int*   rows     = (const int*)d_in[2];
    const int*   cols     = (const int*)d_in[3];
    const float* vals     = (const float*)d_in[4];

    const int nnz        = in_sizes[2];
    const int user_elems = in_sizes[0];   // n_users * DIM

    float* user_out = (float*)d_out;
    float* item_out = (float*)d_out + (size_t)user_elems;

    // Harness does not re-zero d_out between timed replays.
    hipMemsetAsync(d_out, 0, (size_t)out_size * sizeof(float), stream);

    const int block = 256;                 // 4 waves/block
    const int grid  = 2048;                // 8192 waves, grid-stride over edges
    lightgcn_scatter<<<grid, block, 0, stream>>>(user_emb, item_emb, rows, cols,
                                                 vals, user_out, item_out, nnz);
}

// Round 2
// 2507.322 us; speedup vs baseline: 1.6016x; 1.6016x over previous
//
#include <hip/hip_runtime.h>

// LightGCN conv via counting-sort into per-row buckets, then gather-accumulate.
// Pipeline: count -> exclusive scan (in place) -> scatter pairs -> accumulate.
// No float atomics: each output row is produced by exactly one wave.

constexpr int DIM = 64;

// ---------------- fallback (round-1) atomic kernel ----------------
__global__ void lightgcn_scatter_atomic(const float* __restrict__ user_emb,
                                        const float* __restrict__ item_emb,
                                        const int* __restrict__ rows,
                                        const int* __restrict__ cols,
                                        const float* __restrict__ vals,
                                        float* __restrict__ user_out,
                                        float* __restrict__ item_out,
                                        int nnz) {
    const int lane   = threadIdx.x & 63;
    const int wave   = (blockIdx.x * blockDim.x + threadIdx.x) >> 6;
    const int nwaves = (gridDim.x * blockDim.x) >> 6;
    for (int e = wave; e < nnz; e += nwaves) {
        const int r = rows[e];
        const int c = cols[e];
        const float v = vals[e];
        atomicAdd(&user_out[(size_t)r * DIM + lane], v * item_emb[(size_t)c * DIM + lane]);
        atomicAdd(&item_out[(size_t)c * DIM + lane], v * user_emb[(size_t)r * DIM + lane]);
    }
}

// ---------------- stage 1: count ----------------
__global__ void count_edges(const int* __restrict__ rows,
                            const int* __restrict__ cols,
                            int nnz, int* __restrict__ u_cnt, int* __restrict__ i_cnt) {
    int i = blockIdx.x * blockDim.x + threadIdx.x;
    const int stride = gridDim.x * blockDim.x;
    for (; i < nnz; i += stride) {
        atomicAdd(&u_cnt[rows[i]], 1);
        atomicAdd(&i_cnt[cols[i]], 1);
    }
}

// ---------------- stage 2: exclusive scan, in place (2 blocks: users, items) --
__global__ void exscan_inplace(int* __restrict__ arr0, int n0,
                               int* __restrict__ arr1, int n1) {
    int* arr = (blockIdx.x == 0) ? arr0 : arr1;
    const int n = (blockIdx.x == 0) ? n0 : n1;
    __shared__ int s[1024];
    int carry = 0;
    for (int base = 0; base < n; base += 1024) {
        const int i = base + (int)threadIdx.x;
        const int x = (i < n) ? arr[i] : 0;
        s[threadIdx.x] = x;
        __syncthreads();
        for (int off = 1; off < 1024; off <<= 1) {
            const int t = (threadIdx.x >= (unsigned)off) ? s[threadIdx.x - off] : 0;
            __syncthreads();
            s[threadIdx.x] += t;
            __syncthreads();
        }
        const int inc = s[threadIdx.x];
        if (i < n) arr[i] = carry + inc - x;     // exclusive
        const int total = s[1023];
        __syncthreads();                         // s reused next chunk
        carry += total;
    }
}

// ---------------- stage 3: scatter (claims slots; offsets become end-offsets) --
__global__ void scatter_edges(const int* __restrict__ rows,
                              const int* __restrict__ cols,
                              const float* __restrict__ vals, int nnz,
                              int* __restrict__ u_off, int* __restrict__ i_off,
                              uint2* __restrict__ u_pairs, uint2* __restrict__ i_pairs) {
    int i = blockIdx.x * blockDim.x + threadIdx.x;
    const int stride = gridDim.x * blockDim.x;
    for (; i < nnz; i += stride) {
        const int r = rows[i];
        const int c = cols[i];
        const unsigned vbits = __float_as_uint(vals[i]);
        const int su = atomicAdd(&u_off[r], 1);
        u_pairs[su] = make_uint2((unsigned)c, vbits);
        const int si = atomicAdd(&i_off[c], 1);
        i_pairs[si] = make_uint2((unsigned)r, vbits);
    }
}

// ---------------- stage 4: accumulate (one wave per output row) ----------------
// After scatter, off[r] = end of row r; start(r) = (r==0) ? 0 : off[r-1].
__global__ void accumulate_rows(const float* __restrict__ emb,
                                const uint2* __restrict__ pairs,
                                const int* __restrict__ off,
                                int nrows, float* __restrict__ out) {
    const int lane = threadIdx.x & 63;
    const int w = (blockIdx.x * blockDim.x + threadIdx.x) >> 6;
    if (w >= nrows) return;
    const int start = (w == 0) ? 0 : off[w - 1];
    const int end = off[w];
    float acc = 0.f;
    int e = start;
    for (; e + 4 <= end; e += 4) {
        const uint2 p0 = pairs[e + 0];
        const uint2 p1 = pairs[e + 1];
        const uint2 p2 = pairs[e + 2];
        const uint2 p3 = pairs[e + 3];
        const float g0 = emb[(size_t)p0.x * DIM + lane];
        const float g1 = emb[(size_t)p1.x * DIM + lane];
        const float g2 = emb[(size_t)p2.x * DIM + lane];
        const float g3 = emb[(size_t)p3.x * DIM + lane];
        acc = fmaf(__uint_as_float(p0.y), g0, acc);
        acc = fmaf(__uint_as_float(p1.y), g1, acc);
        acc = fmaf(__uint_as_float(p2.y), g2, acc);
        acc = fmaf(__uint_as_float(p3.y), g3, acc);
    }
    for (; e < end; ++e) {
        const uint2 p = pairs[e];
        acc = fmaf(__uint_as_float(p.y), emb[(size_t)p.x * DIM + lane], acc);
    }
    out[(size_t)w * DIM + lane] = acc;
}

extern "C" void kernel_launch(void* const* d_in, const int* in_sizes, int n_in,
                              void* d_out, int out_size, void* d_ws, size_t ws_size,
                              hipStream_t stream) {
    const float* user_emb = (const float*)d_in[0];
    const float* item_emb = (const float*)d_in[1];
    const int*   rows     = (const int*)d_in[2];
    const int*   cols     = (const int*)d_in[3];
    const float* vals     = (const float*)d_in[4];

    const int nnz     = in_sizes[2];
    const int n_users = in_sizes[0] / DIM;
    const int n_items = in_sizes[1] / DIM;

    float* user_out = (float*)d_out;
    float* item_out = (float*)d_out + (size_t)in_sizes[0];

    // Workspace layout (element offsets into int/byte space):
    //   u_off: n_users ints, 128B-align, i_off: n_items ints, then pair buckets.
    const size_t u_off_elems = ((size_t)n_users + 31) & ~(size_t)31;
    const size_t i_off_elems = ((size_t)n_items + 31) & ~(size_t)31;
    const size_t cnt_bytes   = (u_off_elems + i_off_elems) * sizeof(int);
    const size_t pairs_off   = (cnt_bytes + 127) & ~(size_t)127;
    const size_t need        = pairs_off + 2 * (size_t)nnz * sizeof(uint2);

    if (ws_size < need) {
        // Fallback: round-1 atomic version.
        hipMemsetAsync(d_out, 0, (size_t)out_size * sizeof(float), stream);
        lightgcn_scatter_atomic<<<2048, 256, 0, stream>>>(user_emb, item_emb, rows,
                                                          cols, vals, user_out,
                                                          item_out, nnz);
        return;
    }

    int* u_off = (int*)d_ws;
    int* i_off = u_off + u_off_elems;
    uint2* u_pairs = (uint2*)((char*)d_ws + pairs_off);
    uint2* i_pairs = u_pairs + (size_t)nnz;

    hipMemsetAsync(d_ws, 0, cnt_bytes, stream);

    const int block = 256;
    const int grid_edges = 2048;
    count_edges<<<grid_edges, block, 0, stream>>>(rows, cols, nnz, u_off, i_off);
    exscan_inplace<<<2, 1024, 0, stream>>>(u_off, n_users, i_off, n_items);
    scatter_edges<<<grid_edges, block, 0, stream>>>(rows, cols, vals, nnz,
                                                    u_off, i_off, u_pairs, i_pairs);

    const int waves_per_block = block / 64;
    const int grid_u = (n_users + waves_per_block - 1) / waves_per_block;
    const int grid_i = (n_items + waves_per_block - 1) / waves_per_block;
    accumulate_rows<<<grid_u, block, 0, stream>>>(item_emb, u_pairs, u_off,
                                                  n_users, user_out);
    accumulate_rows<<<grid_i, block, 0, stream>>>(user_emb, i_pairs, i_off,
                                                  n_items, item_out);
}